// Round 3
// baseline (430.717 us; speedup 1.0000x reference)
//
#include <hip/hip_runtime.h>

#define N_NODES 100000
#define N_EDGES 1000000
#define D 64

// ============ fast path: CSR-by-dst build, then gather (no float atomics) ============

// Histogram of destination degrees.
__global__ __launch_bounds__(256) void gine_hist(const int* __restrict__ ei,
                                                 int* __restrict__ deg) {
    int e = blockIdx.x * 256 + threadIdx.x;
    if (e < N_EDGES) atomicAdd(&deg[ei[N_EDGES + e]], 1);
}

// Single-block exclusive scan of deg[0..N_NODES) -> row_start, counter (copy).
__global__ __launch_bounds__(1024) void gine_scan(const int* __restrict__ deg,
                                                  int* __restrict__ row_start,
                                                  int* __restrict__ counter) {
    __shared__ int wsum[16];
    __shared__ int carry;
    int tid = threadIdx.x;
    int lane = tid & 63, wid = tid >> 6;
    if (tid == 0) carry = 0;
    __syncthreads();
    for (int base = 0; base < N_NODES; base += 1024) {
        int i = base + tid;
        int v = (i < N_NODES) ? deg[i] : 0;
        int s = v;  // inclusive wave scan
        #pragma unroll
        for (int off = 1; off < 64; off <<= 1) {
            int t = __shfl_up(s, off, 64);
            if (lane >= off) s += t;
        }
        if (lane == 63) wsum[wid] = s;
        __syncthreads();                       // sync_A: wsum ready, carry from prev iter visible
        if (tid < 16) {
            int wv = wsum[tid];
            int ss = wv;
            #pragma unroll
            for (int off = 1; off < 16; off <<= 1) {
                int t = __shfl_up(ss, off, 16);
                if (tid >= off) ss += t;
            }
            wsum[tid] = ss - wv;               // exclusive wave offsets
        }
        __syncthreads();                       // sync_B
        int excl = carry + wsum[wid] + (s - v);
        if (i < N_NODES) { row_start[i] = excl; counter[i] = excl; }
        __syncthreads();                       // sync_C: all reads of carry/wsum done
        if (tid == 1023) carry = excl + v;     // chunk total -> carry for next iter
    }
    __syncthreads();
    if (tid == 0) row_start[N_NODES] = carry;  // == N_EDGES
}

// Scatter (edge_id, src) into dst-sorted order.
__global__ __launch_bounds__(256) void gine_fill(const int* __restrict__ ei,
                                                 int* __restrict__ counter,
                                                 int* __restrict__ eids,
                                                 int* __restrict__ srcs) {
    int e = blockIdx.x * 256 + threadIdx.x;
    if (e < N_EDGES) {
        int t = ei[N_EDGES + e];
        int pos = atomicAdd(&counter[t], 1);
        eids[pos] = e;
        srcs[pos] = ei[e];
    }
}

// Fused: per-node gather-sum of relu(x[src]+ea[e]) + (1+eps)*x, then
// in-wave 64x64 linear + bias + relu. One wave per node, lane = feature.
__global__ __launch_bounds__(256) void gine_agg(const float* __restrict__ x,
                                                const float* __restrict__ ea,
                                                const int* __restrict__ row_start,
                                                const int* __restrict__ eids,
                                                const int* __restrict__ srcs,
                                                const float* __restrict__ W,
                                                const float* __restrict__ bias,
                                                const float* __restrict__ eps,
                                                float* __restrict__ out) {
    __shared__ float Wl[D][D + 1];   // +1 pad: lane o reads Wl[o][dd] -> bank (o+dd)%32, 2-way = free
    __shared__ float hl[4][D + 1];
    __shared__ float bl[D];
    int tid = threadIdx.x;
    for (int i = tid; i < D * D; i += 256) Wl[i >> 6][i & 63] = W[i];
    if (tid < D) bl[tid] = bias[tid];
    __syncthreads();

    int wid = tid >> 6, d = tid & 63;
    int node = blockIdx.x * 4 + wid;
    float acc = 0.0f;
    if (node < N_NODES) {
        int beg = row_start[node], end = row_start[node + 1];
        for (int k = beg; k < end; ++k) {
            int e = eids[k], s = srcs[k];
            float m = x[(long long)s * D + d] + ea[(long long)e * D + d];
            acc += fmaxf(m, 0.0f);
        }
        acc = fmaf(1.0f + eps[0], x[(long long)node * D + d], acc);
    }
    hl[wid][d] = acc;
    __syncthreads();
    if (node < N_NODES) {
        float o = bl[d];
        #pragma unroll
        for (int dd = 0; dd < D; ++dd) o = fmaf(hl[wid][dd], Wl[d][dd], o);
        out[(long long)node * D + d] = fmaxf(o, 0.0f);
    }
}

// ============ fallback path (atomic scatter, round-2 version) ============

__global__ __launch_bounds__(256) void gine_init(const float* __restrict__ x,
                                                 const float* __restrict__ eps,
                                                 float* __restrict__ out, int n4) {
    int i = blockIdx.x * blockDim.x + threadIdx.x;
    float s = 1.0f + eps[0];
    if (i < n4) {
        float4 v = ((const float4*)x)[i];
        v.x *= s; v.y *= s; v.z *= s; v.w *= s;
        ((float4*)out)[i] = v;
    }
}

__global__ __launch_bounds__(256) void gine_edges(const float* __restrict__ x,
                                                  const int* __restrict__ ei,
                                                  const float* __restrict__ ea,
                                                  float* __restrict__ out) {
    int e = blockIdx.x * (blockDim.x >> 6) + (threadIdx.x >> 6);
    int d = threadIdx.x & 63;
    if (e < N_EDGES) {
        int s = ei[e];
        int t = ei[N_EDGES + e];
        float m = x[(long long)s * D + d] + ea[(long long)e * D + d];
        m = fmaxf(m, 0.0f);
        atomicAdd(&out[(long long)t * D + d], m);
    }
}

__global__ __launch_bounds__(256) void gine_linear(float* __restrict__ h,
                                                   const float* __restrict__ W,
                                                   const float* __restrict__ b) {
    __shared__ float Wl[D][D + 1];
    __shared__ float bl[D];
    int tid = threadIdx.x;
    for (int i = tid; i < D * D; i += 256) Wl[i >> 6][i & 63] = W[i];
    if (tid < D) bl[tid] = b[tid];
    __syncthreads();
    int o = tid & 63;
    int row = blockIdx.x * 4 + (tid >> 6);
    if (row < N_NODES) {
        const float* hr = h + (long long)row * D;
        float acc = bl[o];
        #pragma unroll
        for (int d = 0; d < D; ++d) acc = fmaf(hr[d], Wl[o][d], acc);
        h[(long long)row * D + o] = fmaxf(acc, 0.0f);
    }
}

extern "C" void kernel_launch(void* const* d_in, const int* in_sizes, int n_in,
                              void* d_out, int out_size, void* d_ws, size_t ws_size,
                              hipStream_t stream) {
    const float* x   = (const float*)d_in[0];
    const int*   ei  = (const int*)d_in[1];   // int32 on device (harness narrows int64)
    const float* ea  = (const float*)d_in[2];
    const float* W   = (const float*)d_in[3];
    const float* b   = (const float*)d_in[4];
    const float* eps = (const float*)d_in[5];
    float* out = (float*)d_out;

    // ws layout: deg[N] | row_start[N+1] | counter[N] | eids[E] | srcs[E]
    size_t need = ((size_t)N_NODES * 2 + (N_NODES + 1) + (size_t)N_EDGES * 2) * sizeof(int);
    if (ws_size >= need) {
        int* deg       = (int*)d_ws;
        int* row_start = deg + N_NODES;
        int* counter   = row_start + N_NODES + 1;
        int* eids      = counter + N_NODES;
        int* srcs      = eids + N_EDGES;

        hipMemsetAsync(deg, 0, (size_t)N_NODES * sizeof(int), stream);
        gine_hist<<<(N_EDGES + 255) / 256, 256, 0, stream>>>(ei, deg);
        gine_scan<<<1, 1024, 0, stream>>>(deg, row_start, counter);
        gine_fill<<<(N_EDGES + 255) / 256, 256, 0, stream>>>(ei, counter, eids, srcs);
        gine_agg<<<(N_NODES + 3) / 4, 256, 0, stream>>>(x, ea, row_start, eids, srcs,
                                                        W, b, eps, out);
    } else {
        int n4 = (N_NODES * D) / 4;
        gine_init<<<(n4 + 255) / 256, 256, 0, stream>>>(x, eps, out, n4);
        gine_edges<<<(N_EDGES + 3) / 4, 256, 0, stream>>>(x, ei, ea, out);
        gine_linear<<<(N_NODES + 3) / 4, 256, 0, stream>>>(out, W, b);
    }
}

// Round 4
// 264.322 us; speedup vs baseline: 1.6295x; 1.6295x over previous
//
#include <hip/hip_runtime.h>

#define N_NODES 100000
#define N_EDGES 1000000
#define D 64
#define NB1 ((N_NODES + 1023) / 1024)   // 98 scan chunks of 1024

// ============ CSR-by-dst build ============

// Histogram of destination degrees.
__global__ __launch_bounds__(256) void gine_hist(const int* __restrict__ ei,
                                                 int* __restrict__ deg) {
    int e = blockIdx.x * 256 + threadIdx.x;
    if (e < N_EDGES) atomicAdd(&deg[ei[N_EDGES + e]], 1);
}

// Scan stage 1: per-block (1024 elems, 4/thread) exclusive scan + block total.
__global__ __launch_bounds__(256) void gine_scan1(const int* __restrict__ deg,
                                                  int* __restrict__ excl,
                                                  int* __restrict__ bs) {
    __shared__ int wt[4];
    int tid = threadIdx.x, lane = tid & 63, wid = tid >> 6;
    int i0 = blockIdx.x * 1024 + tid * 4;
    int v0 = 0, v1 = 0, v2 = 0, v3 = 0;
    if (i0 + 3 < N_NODES) {
        int4 q = *(const int4*)(deg + i0);
        v0 = q.x; v1 = q.y; v2 = q.z; v3 = q.w;
    } else if (i0 < N_NODES) {
        v0 = deg[i0];
        if (i0 + 1 < N_NODES) v1 = deg[i0 + 1];
        if (i0 + 2 < N_NODES) v2 = deg[i0 + 2];
    }
    int tsum = v0 + v1 + v2 + v3;
    int s = tsum;  // inclusive wave scan of thread sums
    #pragma unroll
    for (int off = 1; off < 64; off <<= 1) {
        int t = __shfl_up(s, off, 64);
        if (lane >= off) s += t;
    }
    if (lane == 63) wt[wid] = s;
    __syncthreads();
    int woff = 0;
    #pragma unroll
    for (int w = 0; w < 4; ++w) if (w < wid) woff += wt[w];
    int e0 = woff + s - tsum;
    if (i0 + 3 < N_NODES) {
        int4 q; q.x = e0; q.y = e0 + v0; q.z = e0 + v0 + v1; q.w = e0 + v0 + v1 + v2;
        *(int4*)(excl + i0) = q;
    } else if (i0 < N_NODES) {
        excl[i0] = e0;
        if (i0 + 1 < N_NODES) excl[i0 + 1] = e0 + v0;
        if (i0 + 2 < N_NODES) excl[i0 + 2] = e0 + v0 + v1;
    }
    if (tid == 255) bs[blockIdx.x] = woff + s;  // block total
}

// Scan stage 2: exclusive scan of the NB1 block totals (one small block).
__global__ __launch_bounds__(128) void gine_scan2(int* __restrict__ bs) {
    __shared__ int wt[2];
    int tid = threadIdx.x, lane = tid & 63, wid = tid >> 6;
    int v = (tid < NB1) ? bs[tid] : 0;
    int s = v;
    #pragma unroll
    for (int off = 1; off < 64; off <<= 1) {
        int t = __shfl_up(s, off, 64);
        if (lane >= off) s += t;
    }
    if (lane == 63) wt[wid] = s;
    __syncthreads();
    int woff = (wid == 1) ? wt[0] : 0;
    if (tid < NB1) bs[tid] = woff + s - v;  // exclusive
}

// Scan stage 3: add block offsets; produce row_start and counter copies.
__global__ __launch_bounds__(256) void gine_scan3(const int* __restrict__ bs,
                                                  int* __restrict__ row_start,
                                                  int* __restrict__ counter) {
    int i = blockIdx.x * 256 + threadIdx.x;
    if (i < N_NODES) {
        int rs = row_start[i] + bs[i >> 10];
        row_start[i] = rs;
        counter[i] = rs;
    }
    if (blockIdx.x == 0 && threadIdx.x == 0) row_start[N_NODES] = N_EDGES;
}

// Scatter packed (edge_id, src) into dst-sorted order — one 8B write/edge.
__global__ __launch_bounds__(256) void gine_fill(const int* __restrict__ ei,
                                                 int* __restrict__ counter,
                                                 int2* __restrict__ pairs) {
    int e = blockIdx.x * 256 + threadIdx.x;
    if (e < N_EDGES) {
        int t = ei[N_EDGES + e];
        int pos = atomicAdd(&counter[t], 1);
        pairs[pos] = make_int2(e, ei[e]);
    }
}

// Fused gather + (1+eps)*x + 64x64 linear + relu. One wave/node, lane=feature.
// Edge loop: masked unroll-8 -> ~16 row loads in flight (MLP for latency).
__global__ __launch_bounds__(256) void gine_agg(const float* __restrict__ x,
                                                const float* __restrict__ ea,
                                                const int* __restrict__ row_start,
                                                const int2* __restrict__ pairs,
                                                const float* __restrict__ W,
                                                const float* __restrict__ bias,
                                                const float* __restrict__ eps,
                                                float* __restrict__ out) {
    __shared__ float Wl[D][D + 1];   // bank (d+dd)%32: 2 lanes/bank = free
    __shared__ float hl[4][D + 1];
    __shared__ float bl[D];
    int tid = threadIdx.x;
    for (int i = tid; i < D * D; i += 256) Wl[i >> 6][i & 63] = W[i];
    if (tid < D) bl[tid] = bias[tid];
    __syncthreads();

    int wid = tid >> 6, d = tid & 63;
    int node = blockIdx.x * 4 + wid;
    float acc = 0.0f;
    if (node < N_NODES) {
        int beg = row_start[node], end = row_start[node + 1];
        int ke = end - 1;
        for (int k = beg; k < end; k += 8) {
            int2 p0 = pairs[k];
            int2 p1 = pairs[min(k + 1, ke)];
            int2 p2 = pairs[min(k + 2, ke)];
            int2 p3 = pairs[min(k + 3, ke)];
            int2 p4 = pairs[min(k + 4, ke)];
            int2 p5 = pairs[min(k + 5, ke)];
            int2 p6 = pairs[min(k + 6, ke)];
            int2 p7 = pairs[min(k + 7, ke)];
            float m0 = fmaxf(x[(long long)p0.y * D + d] + ea[(long long)p0.x * D + d], 0.0f);
            float m1 = fmaxf(x[(long long)p1.y * D + d] + ea[(long long)p1.x * D + d], 0.0f);
            float m2 = fmaxf(x[(long long)p2.y * D + d] + ea[(long long)p2.x * D + d], 0.0f);
            float m3 = fmaxf(x[(long long)p3.y * D + d] + ea[(long long)p3.x * D + d], 0.0f);
            float m4 = fmaxf(x[(long long)p4.y * D + d] + ea[(long long)p4.x * D + d], 0.0f);
            float m5 = fmaxf(x[(long long)p5.y * D + d] + ea[(long long)p5.x * D + d], 0.0f);
            float m6 = fmaxf(x[(long long)p6.y * D + d] + ea[(long long)p6.x * D + d], 0.0f);
            float m7 = fmaxf(x[(long long)p7.y * D + d] + ea[(long long)p7.x * D + d], 0.0f);
            if (k + 1 >= end) m1 = 0.0f;
            if (k + 2 >= end) m2 = 0.0f;
            if (k + 3 >= end) m3 = 0.0f;
            if (k + 4 >= end) m4 = 0.0f;
            if (k + 5 >= end) m5 = 0.0f;
            if (k + 6 >= end) m6 = 0.0f;
            if (k + 7 >= end) m7 = 0.0f;
            acc += ((m0 + m1) + (m2 + m3)) + ((m4 + m5) + (m6 + m7));
        }
        acc = fmaf(1.0f + eps[0], x[(long long)node * D + d], acc);
    }
    hl[wid][d] = acc;
    __syncthreads();
    if (node < N_NODES) {
        float o = bl[d];
        #pragma unroll
        for (int dd = 0; dd < D; ++dd) o = fmaf(hl[wid][dd], Wl[d][dd], o);
        out[(long long)node * D + d] = fmaxf(o, 0.0f);
    }
}

// ============ fallback path (atomic scatter, round-2 version) ============

__global__ __launch_bounds__(256) void gine_init(const float* __restrict__ x,
                                                 const float* __restrict__ eps,
                                                 float* __restrict__ out, int n4) {
    int i = blockIdx.x * blockDim.x + threadIdx.x;
    float s = 1.0f + eps[0];
    if (i < n4) {
        float4 v = ((const float4*)x)[i];
        v.x *= s; v.y *= s; v.z *= s; v.w *= s;
        ((float4*)out)[i] = v;
    }
}

__global__ __launch_bounds__(256) void gine_edges(const float* __restrict__ x,
                                                  const int* __restrict__ ei,
                                                  const float* __restrict__ ea,
                                                  float* __restrict__ out) {
    int e = blockIdx.x * (blockDim.x >> 6) + (threadIdx.x >> 6);
    int d = threadIdx.x & 63;
    if (e < N_EDGES) {
        int s = ei[e];
        int t = ei[N_EDGES + e];
        float m = x[(long long)s * D + d] + ea[(long long)e * D + d];
        m = fmaxf(m, 0.0f);
        atomicAdd(&out[(long long)t * D + d], m);
    }
}

__global__ __launch_bounds__(256) void gine_linear(float* __restrict__ h,
                                                   const float* __restrict__ W,
                                                   const float* __restrict__ b) {
    __shared__ float Wl[D][D + 1];
    __shared__ float bl[D];
    int tid = threadIdx.x;
    for (int i = tid; i < D * D; i += 256) Wl[i >> 6][i & 63] = W[i];
    if (tid < D) bl[tid] = b[tid];
    __syncthreads();
    int o = tid & 63;
    int row = blockIdx.x * 4 + (tid >> 6);
    if (row < N_NODES) {
        const float* hr = h + (long long)row * D;
        float acc = bl[o];
        #pragma unroll
        for (int d = 0; d < D; ++d) acc = fmaf(hr[d], Wl[o][d], acc);
        h[(long long)row * D + o] = fmaxf(acc, 0.0f);
    }
}

extern "C" void kernel_launch(void* const* d_in, const int* in_sizes, int n_in,
                              void* d_out, int out_size, void* d_ws, size_t ws_size,
                              hipStream_t stream) {
    const float* x   = (const float*)d_in[0];
    const int*   ei  = (const int*)d_in[1];   // int32 on device (harness narrows int64)
    const float* ea  = (const float*)d_in[2];
    const float* W   = (const float*)d_in[3];
    const float* b   = (const float*)d_in[4];
    const float* eps = (const float*)d_in[5];
    float* out = (float*)d_out;

    // ws layout: pairs[E] int2 (8B-aligned at front) | deg[N] | row_start[N+1] | counter[N] | bs[128]
    size_t need = (size_t)N_EDGES * 8 + ((size_t)N_NODES * 3 + 1 + 128) * sizeof(int);
    if (ws_size >= need) {
        int2* pairs     = (int2*)d_ws;
        int* deg        = (int*)(pairs + N_EDGES);
        int* row_start  = deg + N_NODES;
        int* counter    = row_start + N_NODES + 1;
        int* bs         = counter + N_NODES;

        hipMemsetAsync(deg, 0, (size_t)N_NODES * sizeof(int), stream);
        gine_hist<<<(N_EDGES + 255) / 256, 256, 0, stream>>>(ei, deg);
        gine_scan1<<<NB1, 256, 0, stream>>>(deg, row_start, bs);
        gine_scan2<<<1, 128, 0, stream>>>(bs);
        gine_scan3<<<(N_NODES + 255) / 256, 256, 0, stream>>>(bs, row_start, counter);
        gine_fill<<<(N_EDGES + 255) / 256, 256, 0, stream>>>(ei, counter, pairs);
        gine_agg<<<(N_NODES + 3) / 4, 256, 0, stream>>>(x, ea, row_start, pairs,
                                                        W, b, eps, out);
    } else {
        int n4 = (N_NODES * D) / 4;
        gine_init<<<(n4 + 255) / 256, 256, 0, stream>>>(x, eps, out, n4);
        gine_edges<<<(N_EDGES + 3) / 4, 256, 0, stream>>>(x, ei, ea, out);
        gine_linear<<<(N_NODES + 3) / 4, 256, 0, stream>>>(out, W, b);
    }
}